// Round 9
// baseline (214.432 us; speedup 1.0000x reference)
//
#include <hip/hip_runtime.h>

// ---------- types / helpers ----------
typedef __attribute__((ext_vector_type(8))) short short8;   // 8 bf16 = 4 VGPRs
typedef __attribute__((ext_vector_type(4))) short bf16x4;   // 4 bf16 = 2 VGPRs
typedef __attribute__((ext_vector_type(4))) float floatx4;  // MFMA C/D
typedef __attribute__((ext_vector_type(4))) float f32x4;

__device__ __forceinline__ short f2bf(float f) {
    union { float f; unsigned u; } v;
    v.f = f;
    unsigned r = v.u + 0x7fffu + ((v.u >> 16) & 1u);  // RNE
    return (short)(r >> 16);
}
__device__ __forceinline__ short8 cvt8(f32x4 a, f32x4 b) {
    short8 r;
    r[0] = f2bf(a[0]); r[1] = f2bf(a[1]); r[2] = f2bf(a[2]); r[3] = f2bf(a[3]);
    r[4] = f2bf(b[0]); r[5] = f2bf(b[1]); r[6] = f2bf(b[2]); r[7] = f2bf(b[3]);
    return r;
}
// round-half-up f32->bf16 pack of 4
__device__ __forceinline__ bf16x4 pack4(float a, float b, float c, float d) {
    union { float f; unsigned u; } x;
    unsigned ua, ub, uc, ud;
    x.f = a; ua = (x.u + 0x8000u) >> 16;
    x.f = b; ub = (x.u + 0x8000u) >> 16;
    x.f = c; uc = (x.u + 0x8000u) >> 16;
    x.f = d; ud = (x.u + 0x8000u) >> 16;
    union { bf16x4 s; unsigned u2[2]; } r;
    r.u2[0] = ua | (ub << 16);
    r.u2[1] = uc | (ud << 16);
    return r.s;
}

#define MFMA_BF16(a, b, c) __builtin_amdgcn_mfma_f32_16x16x32_bf16((a), (b), (c), 0, 0, 0)

__device__ __forceinline__ floatx4 mfma16(bf16x4 a, bf16x4 b, floatx4 c) {
#if __has_builtin(__builtin_amdgcn_mfma_f32_16x16x16bf16_1k)
    return __builtin_amdgcn_mfma_f32_16x16x16bf16_1k(a, b, c, 0, 0, 0);
#else
    floatx4 d;
    asm volatile("v_mfma_f32_16x16x16_bf16 %0, %1, %2, %3"
                 : "=&v"(d) : "v"(a), "v"(b), "v"(c));
    return d;
#endif
}

__device__ __forceinline__ float fast_exp2(float x) {
#if __has_builtin(__builtin_amdgcn_exp2f)
    return __builtin_amdgcn_exp2f(x);
#else
    return exp2f(x);
#endif
}

// scale(1/8) * log2(e): softmax in exp2 domain, folded into Q at proj time
#define QSCALE_LOG2E 0.18033688011112042f

// LDS row stride for A chunks: 128 data + 8 pad = 136 shorts (272B = 68 banks
// -> uniform bank spread; 64B stride was an 8-way conflict, m136)
#define APAD 136

// ---------- 1) all 4 weight transposes in one launch ----------
__global__ __launch_bounds__(256) void transpose_all(const float* __restrict__ Wq,
                                                     const float* __restrict__ Wk,
                                                     const float* __restrict__ Wv,
                                                     const float* __restrict__ Wo,
                                                     short* __restrict__ WqT,
                                                     short* __restrict__ WkT,
                                                     short* __restrict__ WvT,
                                                     short* __restrict__ WoT) {
    const int z = blockIdx.z;
    const float* src = (z == 0) ? Wq : (z == 1) ? Wk : (z == 2) ? Wv : Wo;
    short* dst = (z == 0) ? WqT : (z == 1) ? WkT : (z == 2) ? WvT : WoT;
    const int R = (z < 3) ? 1024 : 512;
    const int C = (z < 3) ? 512 : 1024;
    const int c0 = blockIdx.x * 32;
    const int r0 = blockIdx.y * 32;
    if (c0 >= C || r0 >= R) return;
    __shared__ float tile[32][33];
    const int tx = threadIdx.x;
    const int ty = threadIdx.y;
#pragma unroll
    for (int i = 0; i < 32; i += 8)
        tile[ty + i][tx] = src[(r0 + ty + i) * C + c0 + tx];
    __syncthreads();
#pragma unroll
    for (int i = 0; i < 32; i += 8)
        dst[(c0 + ty + i) * R + r0 + tx] = f2bf(tile[tx][ty + i]);
}

// ---------- 2) fused QKV projection GEMM: A-chunk-stationary, barrier-sparse ----------
// C[4096][512] = A_f32[4096][1024] @ W ; WT[512][1024] bf16.
// Block 256 thr (4 waves), BM=64 x BN=128. A staged in LDS in BK=128 chunks
// (double-buffered, 1 barrier/chunk = 8 total). B read straight from global
// (L2-resident, no barriers between sub-steps -> compiler pipelines deeply).
__global__ __launch_bounds__(256, 3) void gemm_qkv(const float* __restrict__ x,
                                                   const float* __restrict__ ctx,
                                                   const short* __restrict__ WqT,
                                                   const short* __restrict__ WkT,
                                                   const short* __restrict__ WvT,
                                                   short* __restrict__ Qw,
                                                   short* __restrict__ Kw,
                                                   short* __restrict__ Vtw) {
    const int z = blockIdx.z;
    const float* A  = (z == 0) ? x : ctx;
    const short* WT = (z == 0) ? WqT : (z == 1) ? WkT : WvT;
    const int tid = threadIdx.x;
    const int w = tid >> 6;
    const int lane = tid & 63;
    const int quad = lane >> 4, ln = lane & 15;
    const int wr = w >> 1, wc = w & 1;
    const int row0 = blockIdx.x * 64;
    const int col0 = blockIdx.y * 128;

    __shared__ __align__(16) short Alds[2][64][APAD];

    const int arow = tid >> 2;        // 0..63
    const int aseg = tid & 3;         // 0..3, 32 k-elements each
    const float* aG = A + (size_t)(row0 + arow) * 1024 + aseg * 32;
    // B pointers: 4 output cols per wave (t), each row of WT is K-contiguous
    const short* bG[4];
#pragma unroll
    for (int t = 0; t < 4; ++t)
        bG[t] = WT + (size_t)(col0 + wc * 64 + t * 16 + ln) * 1024 + quad * 8;

    floatx4 acc[2][4] = {};
    f32x4 areg[8];

    auto loadA = [&](int c) {
#pragma unroll
        for (int i = 0; i < 8; ++i)
            areg[i] = *(const f32x4*)(aG + c * 128 + i * 4);
    };
    auto writeA = [&](int buf) {
#pragma unroll
        for (int i = 0; i < 4; ++i)
            *(short8*)(&Alds[buf][arow][aseg * 32 + i * 8]) = cvt8(areg[2 * i], areg[2 * i + 1]);
    };

    loadA(0);
    writeA(0);
    __syncthreads();

    const int nch = 1024 / 128;  // 8 chunks
    for (int c = 0; c < nch; ++c) {
        const int buf = c & 1;
        const bool more = (c + 1 < nch);
        if (more) loadA(c + 1);  // global loads in flight across the whole chunk compute
#pragma unroll
        for (int s = 0; s < 4; ++s) {
            const int k = c * 128 + s * 32;
            short8 bf4[4];
#pragma unroll
            for (int t = 0; t < 4; ++t) bf4[t] = *(const short8*)(bG[t] + k);
            short8 af[2];
#pragma unroll
            for (int i = 0; i < 2; ++i)
                af[i] = *(const short8*)(&Alds[buf][wr * 32 + i * 16 + ln][s * 32 + quad * 8]);
#pragma unroll
            for (int i = 0; i < 2; ++i)
#pragma unroll
                for (int t = 0; t < 4; ++t)
                    acc[i][t] = MFMA_BF16(af[i], bf4[t], acc[i][t]);
        }
        if (more) {
            writeA(buf ^ 1);
            __syncthreads();
        }
    }

    const float oscale = (z == 0) ? QSCALE_LOG2E : 1.0f;
    short* dst = (z == 0) ? Qw : (z == 1) ? Kw : Vtw;
#pragma unroll
    for (int i = 0; i < 2; ++i)
#pragma unroll
        for (int t = 0; t < 4; ++t)
#pragma unroll
            for (int r = 0; r < 4; ++r) {
                const int R = row0 + wr * 32 + i * 16 + quad * 4 + r;
                const int C = col0 + wc * 64 + t * 16 + ln;
                const int b = R >> 11, n = R & 2047;
                const int h = C >> 6, d = C & 63;
                const short val = f2bf(acc[i][t][r] * oscale);
                if (z < 2)
                    dst[((b * 8 + h) * 2048 + n) * 64 + d] = val;
                else
                    dst[((b * 8 + h) * 64 + d) * 2048 + n] = val;
            }
}

// ---------- 3) flash attention (unchanged from round 8: staged K/V, S^T trick) ----------
__global__ __launch_bounds__(256, 2) void attn_kernel(const short* __restrict__ Q,
                                                      const short* __restrict__ K,
                                                      const short* __restrict__ Vt,
                                                      short* __restrict__ Aw) {
    const int tid = threadIdx.x;
    const int w = tid >> 6;
    const int lane = tid & 63;
    const int quad = lane >> 4;
    const int ln = lane & 15;
    const int q0 = blockIdx.x * 64;
    const int bh = blockIdx.y;  // b*8+h

    __shared__ __align__(16) short klds[2][64][72];
    __shared__ __align__(16) short vlds[2][64][72];

    const short* Qbh = Q + bh * 2048 * 64;
    const short* Kbh = K + bh * 2048 * 64;
    const short* Vbh = Vt + bh * 64 * 2048;

    short8 qf[2];
    {
        const int qrow = q0 + w * 16 + ln;
        qf[0] = *(const short8*)(Qbh + qrow * 64 + quad * 8);
        qf[1] = *(const short8*)(Qbh + qrow * 64 + 32 + quad * 8);
    }

    floatx4 ot[4] = {};   // O^T: lane holds d=dt*16+quad*4+r, qrow=ln
    float lp = 0.f;

    const int sr = tid >> 3;
    const int sc = (tid & 7) * 8;

    auto computeTile = [&](int b) {
        short8 kf[8];
#pragma unroll
        for (int t = 0; t < 4; ++t)
#pragma unroll
            for (int ks = 0; ks < 2; ++ks)
                kf[t * 2 + ks] = *(const short8*)(&klds[b][t * 16 + ln][ks * 32 + quad * 8]);
        bf16x4 vf[16];
#pragma unroll
        for (int dt = 0; dt < 4; ++dt)
#pragma unroll
            for (int t = 0; t < 4; ++t)
                vf[dt * 4 + t] = *(const bf16x4*)(&vlds[b][dt * 16 + ln][t * 16 + quad * 4]);

        floatx4 s[4] = {};
#pragma unroll
        for (int ks = 0; ks < 2; ++ks)
#pragma unroll
            for (int t = 0; t < 4; ++t)
                s[t] = MFMA_BF16(kf[t * 2 + ks], qf[ks], s[t]);

        bf16x4 pf[4];
#pragma unroll
        for (int t = 0; t < 4; ++t) {
            float p0 = fast_exp2(s[t][0]);
            float p1 = fast_exp2(s[t][1]);
            float p2 = fast_exp2(s[t][2]);
            float p3 = fast_exp2(s[t][3]);
            lp += (p0 + p1) + (p2 + p3);
            pf[t] = pack4(p0, p1, p2, p3);
        }
#pragma unroll
        for (int t = 0; t < 4; ++t)
#pragma unroll
            for (int dt = 0; dt < 4; ++dt)
                ot[dt] = mfma16(vf[dt * 4 + t], pf[t], ot[dt]);
    };

    const int nt = 2048 / 64;

    {   // prologue: stage tile 0
        short8 k0 = *(const short8*)(Kbh + tid * 8);
        short8 k1 = *(const short8*)(Kbh + (tid + 256) * 8);
        short8 v0 = *(const short8*)(Vbh + sr * 2048 + sc);
        short8 v1 = *(const short8*)(Vbh + (sr + 32) * 2048 + sc);
        *(short8*)(&klds[0][sr][sc]) = k0;
        *(short8*)(&klds[0][sr + 32][sc]) = k1;
        *(short8*)(&vlds[0][sr][sc]) = v0;
        *(short8*)(&vlds[0][sr + 32][sc]) = v1;
    }
    __syncthreads();

    for (int it = 0; it < nt; ++it) {
        short8 k0, k1, v0, v1;
        const bool more = (it + 1 < nt);
        if (more) {
            const int jn = (it + 1) * 64;
            k0 = *(const short8*)(Kbh + jn * 64 + tid * 8);
            k1 = *(const short8*)(Kbh + jn * 64 + (tid + 256) * 8);
            v0 = *(const short8*)(Vbh + sr * 2048 + jn + sc);
            v1 = *(const short8*)(Vbh + (sr + 32) * 2048 + jn + sc);
        }
        computeTile(it & 1);
        if (more) {
            const int nb = (it + 1) & 1;
            *(short8*)(&klds[nb][sr][sc]) = k0;
            *(short8*)(&klds[nb][sr + 32][sc]) = k1;
            *(short8*)(&vlds[nb][sr][sc]) = v0;
            *(short8*)(&vlds[nb][sr + 32][sc]) = v1;
        }
        __syncthreads();
    }

    lp += __shfl_xor(lp, 16);
    lp += __shfl_xor(lp, 32);
    const float invL = 1.0f / lp;

    const int n = q0 + w * 16 + ln;
    const int b = bh >> 3, h = bh & 7;
    short* abase = Aw + ((size_t)(b * 2048 + n) * 512) + h * 64 + quad * 4;
#pragma unroll
    for (int dt = 0; dt < 4; ++dt)
        *(bf16x4*)(abase + dt * 16) =
            pack4(ot[dt][0] * invL, ot[dt][1] * invL, ot[dt][2] * invL, ot[dt][3] * invL);
}

// ---------- 4) output GEMM + bias: A-chunk-stationary, barrier-sparse ----------
// out_f32[4096][1024] = A_bf16[4096][512] @ Wo + bo; WoT[1024][512] bf16.
// BM=64 x BN=128, BK=128 chunks (4 chunks, 1 barrier each), B direct-from-global.
__global__ __launch_bounds__(256, 2) void gemm_final(const short* __restrict__ A,
                                                     const short* __restrict__ WoT,
                                                     const float* __restrict__ bias,
                                                     float* __restrict__ out) {
    const int tid = threadIdx.x;
    const int w = tid >> 6;
    const int lane = tid & 63;
    const int quad = lane >> 4, ln = lane & 15;
    const int wr = w >> 1, wc = w & 1;
    const int row0 = blockIdx.x * 64;
    const int col0 = blockIdx.y * 128;

    __shared__ __align__(16) short Alds[2][64][APAD];

    const int arow = tid >> 2;
    const int aseg = tid & 3;
    const short* aG = A + (size_t)(row0 + arow) * 512 + aseg * 32;
    const short* bG[4];
#pragma unroll
    for (int t = 0; t < 4; ++t)
        bG[t] = WoT + (size_t)(col0 + wc * 64 + t * 16 + ln) * 512 + quad * 8;

    floatx4 acc[2][4] = {};
    short8 areg[4];

    auto loadA = [&](int c) {
#pragma unroll
        for (int i = 0; i < 4; ++i)
            areg[i] = *(const short8*)(aG + c * 128 + i * 8);
    };
    auto writeA = [&](int buf) {
#pragma unroll
        for (int i = 0; i < 4; ++i)
            *(short8*)(&Alds[buf][arow][aseg * 32 + i * 8]) = areg[i];
    };

    loadA(0);
    writeA(0);
    __syncthreads();

    const int nch = 512 / 128;  // 4 chunks
    for (int c = 0; c < nch; ++c) {
        const int buf = c & 1;
        const bool more = (c + 1 < nch);
        if (more) loadA(c + 1);
#pragma unroll
        for (int s = 0; s < 4; ++s) {
            const int k = c * 128 + s * 32;
            short8 bf4[4];
#pragma unroll
            for (int t = 0; t < 4; ++t) bf4[t] = *(const short8*)(bG[t] + k);
            short8 af[2];
#pragma unroll
            for (int i = 0; i < 2; ++i)
                af[i] = *(const short8*)(&Alds[buf][wr * 32 + i * 16 + ln][s * 32 + quad * 8]);
#pragma unroll
            for (int i = 0; i < 2; ++i)
#pragma unroll
                for (int t = 0; t < 4; ++t)
                    acc[i][t] = MFMA_BF16(af[i], bf4[t], acc[i][t]);
        }
        if (more) {
            writeA(buf ^ 1);
            __syncthreads();
        }
    }

#pragma unroll
    for (int i = 0; i < 2; ++i)
#pragma unroll
        for (int t = 0; t < 4; ++t)
#pragma unroll
            for (int r = 0; r < 4; ++r) {
                const int R = row0 + wr * 32 + i * 16 + quad * 4 + r;
                const int C = col0 + wc * 64 + t * 16 + ln;
                out[(size_t)R * 1024 + C] = acc[i][t][r] + bias[C];
            }
}

// ---------- launcher ----------
extern "C" void kernel_launch(void* const* d_in, const int* in_sizes, int n_in,
                              void* d_out, int out_size, void* d_ws, size_t ws_size,
                              hipStream_t stream) {
    const float* x   = (const float*)d_in[0];  // [2,2048,1024] f32
    const float* ctx = (const float*)d_in[1];
    const float* Wq  = (const float*)d_in[2];  // [1024,512]
    const float* Wk  = (const float*)d_in[3];
    const float* Wv  = (const float*)d_in[4];
    const float* Wo  = (const float*)d_in[5];  // [512,1024]
    const float* bo  = (const float*)d_in[6];  // [1024]
    float* out = (float*)d_out;                // [2,2048,1024] f32

    char* ws = (char*)d_ws;
    size_t off = 0;
    auto alloc = [&](size_t bytes) { char* p = ws + off; off += (bytes + 255) & ~(size_t)255; return p; };

    short* WqT  = (short*)alloc(512 * 1024 * 2);     // [512][1024] bf16
    short* WkT  = (short*)alloc(512 * 1024 * 2);
    short* WvT  = (short*)alloc(512 * 1024 * 2);
    short* WoT  = (short*)alloc(1024 * 512 * 2);     // [1024][512] bf16
    short* Qw   = (short*)alloc((size_t)16 * 2048 * 64 * 2);
    short* Kw   = (short*)alloc((size_t)16 * 2048 * 64 * 2);
    short* Vtw  = (short*)alloc((size_t)16 * 2048 * 64 * 2);
    short* Aw   = (short*)alloc((size_t)4096 * 512 * 2);

    transpose_all<<<dim3(32, 32, 4), dim3(32, 8), 0, stream>>>(Wq, Wk, Wv, Wo, WqT, WkT, WvT, WoT);

    gemm_qkv<<<dim3(64, 4, 3), 256, 0, stream>>>(x, ctx, WqT, WkT, WvT, Qw, Kw, Vtw);

    attn_kernel<<<dim3(32, 16), 256, 0, stream>>>(Qw, Kw, Vtw, Aw);

    gemm_final<<<dim3(64, 8), 256, 0, stream>>>(Aw, WoT, bo, out);
}

// Round 10
// 168.927 us; speedup vs baseline: 1.2694x; 1.2694x over previous
//
#include <hip/hip_runtime.h>

// ---------- types / helpers ----------
typedef __attribute__((ext_vector_type(8))) short short8;   // 8 bf16 = 4 VGPRs
typedef __attribute__((ext_vector_type(4))) short bf16x4;   // 4 bf16 = 2 VGPRs
typedef __attribute__((ext_vector_type(4))) float floatx4;  // MFMA C/D
typedef __attribute__((ext_vector_type(4))) float f32x4;

__device__ __forceinline__ short f2bf(float f) {
    union { float f; unsigned u; } v;
    v.f = f;
    unsigned r = v.u + 0x7fffu + ((v.u >> 16) & 1u);  // RNE
    return (short)(r >> 16);
}
__device__ __forceinline__ short8 cvt8(f32x4 a, f32x4 b) {
    short8 r;
    r[0] = f2bf(a[0]); r[1] = f2bf(a[1]); r[2] = f2bf(a[2]); r[3] = f2bf(a[3]);
    r[4] = f2bf(b[0]); r[5] = f2bf(b[1]); r[6] = f2bf(b[2]); r[7] = f2bf(b[3]);
    return r;
}
// round-half-up f32->bf16 pack of 4
__device__ __forceinline__ bf16x4 pack4(float a, float b, float c, float d) {
    union { float f; unsigned u; } x;
    unsigned ua, ub, uc, ud;
    x.f = a; ua = (x.u + 0x8000u) >> 16;
    x.f = b; ub = (x.u + 0x8000u) >> 16;
    x.f = c; uc = (x.u + 0x8000u) >> 16;
    x.f = d; ud = (x.u + 0x8000u) >> 16;
    union { bf16x4 s; unsigned u2[2]; } r;
    r.u2[0] = ua | (ub << 16);
    r.u2[1] = uc | (ud << 16);
    return r.s;
}

#define MFMA_BF16(a, b, c) __builtin_amdgcn_mfma_f32_16x16x32_bf16((a), (b), (c), 0, 0, 0)

__device__ __forceinline__ floatx4 mfma16(bf16x4 a, bf16x4 b, floatx4 c) {
#if __has_builtin(__builtin_amdgcn_mfma_f32_16x16x16bf16_1k)
    return __builtin_amdgcn_mfma_f32_16x16x16bf16_1k(a, b, c, 0, 0, 0);
#else
    floatx4 d;
    asm volatile("v_mfma_f32_16x16x16_bf16 %0, %1, %2, %3"
                 : "=&v"(d) : "v"(a), "v"(b), "v"(c));
    return d;
#endif
}

__device__ __forceinline__ float fast_exp2(float x) {
#if __has_builtin(__builtin_amdgcn_exp2f)
    return __builtin_amdgcn_exp2f(x);
#else
    return exp2f(x);
#endif
}

// scale(1/8) * log2(e): softmax in exp2 domain, folded into Q at proj time
#define QSCALE_LOG2E 0.18033688011112042f

// LDS row stride 40 shorts = 80 B = 20 banks: 16 rows land on 8 distinct
// 4-bank-wide slots x2 -> 2-way aliasing only (free, m136). 32-short rows
// (64 B = 16 banks) were an 8-way conflict (round-8: 2.36M conflict cycles).
#define TPAD 40

// ---------- 1) all 4 weight transposes in one launch ----------
__global__ __launch_bounds__(256) void transpose_all(const float* __restrict__ Wq,
                                                     const float* __restrict__ Wk,
                                                     const float* __restrict__ Wv,
                                                     const float* __restrict__ Wo,
                                                     short* __restrict__ WqT,
                                                     short* __restrict__ WkT,
                                                     short* __restrict__ WvT,
                                                     short* __restrict__ WoT) {
    const int z = blockIdx.z;
    const float* src = (z == 0) ? Wq : (z == 1) ? Wk : (z == 2) ? Wv : Wo;
    short* dst = (z == 0) ? WqT : (z == 1) ? WkT : (z == 2) ? WvT : WoT;
    const int R = (z < 3) ? 1024 : 512;
    const int C = (z < 3) ? 512 : 1024;
    const int c0 = blockIdx.x * 32;
    const int r0 = blockIdx.y * 32;
    if (c0 >= C || r0 >= R) return;
    __shared__ float tile[32][33];
    const int tx = threadIdx.x;
    const int ty = threadIdx.y;
#pragma unroll
    for (int i = 0; i < 32; i += 8)
        tile[ty + i][tx] = src[(r0 + ty + i) * C + c0 + tx];
    __syncthreads();
#pragma unroll
    for (int i = 0; i < 32; i += 8)
        dst[(c0 + ty + i) * R + r0 + tx] = f2bf(tile[tx][ty + i]);
}

// ---------- 2) fused QKV projection GEMM: coop staging, distance-2 prefetch ----------
// C[4096][512] = A_f32[4096][1024] @ W ; WT[512][1024] bf16.
// Block 256 thr (4 waves), BM=64 x BN=128, BK=32, LDS ping-pong + 2 reg sets:
// at step it: issue loads for it+2, ds_write it+1 (vmcnt covers only it+1's
// loads, issued one full iteration ago), compute it, barrier.
__global__ __launch_bounds__(256, 3) void gemm_qkv(const float* __restrict__ x,
                                                   const float* __restrict__ ctx,
                                                   const short* __restrict__ WqT,
                                                   const short* __restrict__ WkT,
                                                   const short* __restrict__ WvT,
                                                   short* __restrict__ Qw,
                                                   short* __restrict__ Kw,
                                                   short* __restrict__ Vtw) {
    const int z = blockIdx.z;
    const float* A  = (z == 0) ? x : ctx;
    const short* WT = (z == 0) ? WqT : (z == 1) ? WkT : WvT;
    const int tid = threadIdx.x;
    const int w = tid >> 6;
    const int lane = tid & 63;
    const int quad = lane >> 4, ln = lane & 15;
    const int wr = w >> 1, wc = w & 1;
    const int row0 = blockIdx.x * 64;
    const int col0 = blockIdx.y * 128;

    __shared__ __align__(16) short Alds[2][64][TPAD];
    __shared__ __align__(16) short Blds[2][128][TPAD];

    const int srow = tid >> 2;          // 0..63
    const int scol = (tid & 3) * 8;     // 0,8,16,24
    const float* aG = A + (size_t)(row0 + srow) * 1024 + scol;
    const short* bG0 = WT + (size_t)(col0 + srow) * 1024 + scol;
    const short* bG1 = WT + (size_t)(col0 + srow + 64) * 1024 + scol;

    floatx4 acc[2][4] = {};
    f32x4 aR[2][2];
    short8 bR[2][2];

    auto loadStep = [&](int it, int set) {
        const int kk = it * 32;
        aR[set][0] = *(const f32x4*)(aG + kk);
        aR[set][1] = *(const f32x4*)(aG + kk + 4);
        bR[set][0] = *(const short8*)(bG0 + kk);
        bR[set][1] = *(const short8*)(bG1 + kk);
    };
    auto writeStep = [&](int buf, int set) {
        *(short8*)(&Alds[buf][srow][scol]) = cvt8(aR[set][0], aR[set][1]);
        *(short8*)(&Blds[buf][srow][scol]) = bR[set][0];
        *(short8*)(&Blds[buf][srow + 64][scol]) = bR[set][1];
    };

    loadStep(0, 0);
    writeStep(0, 0);
    loadStep(1, 1);
    __syncthreads();

    const int nsteps = 1024 / 32;
    for (int it = 0; it < nsteps; ++it) {
        const int buf = it & 1;
        if (it + 2 < nsteps) loadStep(it + 2, it & 1);       // overwrites step-it regs (already in LDS)
        if (it + 1 < nsteps) writeStep(buf ^ 1, (it + 1) & 1);
        short8 af[2], bf4[4];
#pragma unroll
        for (int i = 0; i < 2; ++i)
            af[i] = *(const short8*)(&Alds[buf][wr * 32 + i * 16 + ln][quad * 8]);
#pragma unroll
        for (int t = 0; t < 4; ++t)
            bf4[t] = *(const short8*)(&Blds[buf][wc * 64 + t * 16 + ln][quad * 8]);
#pragma unroll
        for (int i = 0; i < 2; ++i)
#pragma unroll
            for (int t = 0; t < 4; ++t)
                acc[i][t] = MFMA_BF16(af[i], bf4[t], acc[i][t]);
        __syncthreads();
    }

    const float oscale = (z == 0) ? QSCALE_LOG2E : 1.0f;
    short* dst = (z == 0) ? Qw : (z == 1) ? Kw : Vtw;
#pragma unroll
    for (int i = 0; i < 2; ++i)
#pragma unroll
        for (int t = 0; t < 4; ++t)
#pragma unroll
            for (int r = 0; r < 4; ++r) {
                const int R = row0 + wr * 32 + i * 16 + quad * 4 + r;
                const int C = col0 + wc * 64 + t * 16 + ln;
                const int b = R >> 11, n = R & 2047;
                const int h = C >> 6, d = C & 63;
                const short val = f2bf(acc[i][t][r] * oscale);
                if (z < 2)
                    dst[((b * 8 + h) * 2048 + n) * 64 + d] = val;
                else
                    dst[((b * 8 + h) * 64 + d) * 2048 + n] = val;
            }
}

// ---------- 3) flash attention (round-8 structure: staged K/V, S^T trick) ----------
__global__ __launch_bounds__(256, 2) void attn_kernel(const short* __restrict__ Q,
                                                      const short* __restrict__ K,
                                                      const short* __restrict__ Vt,
                                                      short* __restrict__ Aw) {
    const int tid = threadIdx.x;
    const int w = tid >> 6;
    const int lane = tid & 63;
    const int quad = lane >> 4;
    const int ln = lane & 15;
    const int q0 = blockIdx.x * 64;
    const int bh = blockIdx.y;  // b*8+h

    __shared__ __align__(16) short klds[2][64][72];
    __shared__ __align__(16) short vlds[2][64][72];

    const short* Qbh = Q + bh * 2048 * 64;
    const short* Kbh = K + bh * 2048 * 64;
    const short* Vbh = Vt + bh * 64 * 2048;

    short8 qf[2];
    {
        const int qrow = q0 + w * 16 + ln;
        qf[0] = *(const short8*)(Qbh + qrow * 64 + quad * 8);
        qf[1] = *(const short8*)(Qbh + qrow * 64 + 32 + quad * 8);
    }

    floatx4 ot[4] = {};   // O^T: lane holds d=dt*16+quad*4+r, qrow=ln
    float lp = 0.f;

    const int sr = tid >> 3;
    const int sc = (tid & 7) * 8;

    auto computeTile = [&](int b) {
        short8 kf[8];
#pragma unroll
        for (int t = 0; t < 4; ++t)
#pragma unroll
            for (int ks = 0; ks < 2; ++ks)
                kf[t * 2 + ks] = *(const short8*)(&klds[b][t * 16 + ln][ks * 32 + quad * 8]);
        bf16x4 vf[16];
#pragma unroll
        for (int dt = 0; dt < 4; ++dt)
#pragma unroll
            for (int t = 0; t < 4; ++t)
                vf[dt * 4 + t] = *(const bf16x4*)(&vlds[b][dt * 16 + ln][t * 16 + quad * 4]);

        floatx4 s[4] = {};
#pragma unroll
        for (int ks = 0; ks < 2; ++ks)
#pragma unroll
            for (int t = 0; t < 4; ++t)
                s[t] = MFMA_BF16(kf[t * 2 + ks], qf[ks], s[t]);

        bf16x4 pf[4];
#pragma unroll
        for (int t = 0; t < 4; ++t) {
            float p0 = fast_exp2(s[t][0]);
            float p1 = fast_exp2(s[t][1]);
            float p2 = fast_exp2(s[t][2]);
            float p3 = fast_exp2(s[t][3]);
            lp += (p0 + p1) + (p2 + p3);
            pf[t] = pack4(p0, p1, p2, p3);
        }
#pragma unroll
        for (int t = 0; t < 4; ++t)
#pragma unroll
            for (int dt = 0; dt < 4; ++dt)
                ot[dt] = mfma16(vf[dt * 4 + t], pf[t], ot[dt]);
    };

    const int nt = 2048 / 64;

    {   // prologue: stage tile 0
        short8 k0 = *(const short8*)(Kbh + tid * 8);
        short8 k1 = *(const short8*)(Kbh + (tid + 256) * 8);
        short8 v0 = *(const short8*)(Vbh + sr * 2048 + sc);
        short8 v1 = *(const short8*)(Vbh + (sr + 32) * 2048 + sc);
        *(short8*)(&klds[0][sr][sc]) = k0;
        *(short8*)(&klds[0][sr + 32][sc]) = k1;
        *(short8*)(&vlds[0][sr][sc]) = v0;
        *(short8*)(&vlds[0][sr + 32][sc]) = v1;
    }
    __syncthreads();

    for (int it = 0; it < nt; ++it) {
        short8 k0, k1, v0, v1;
        const bool more = (it + 1 < nt);
        if (more) {
            const int jn = (it + 1) * 64;
            k0 = *(const short8*)(Kbh + jn * 64 + tid * 8);
            k1 = *(const short8*)(Kbh + jn * 64 + (tid + 256) * 8);
            v0 = *(const short8*)(Vbh + sr * 2048 + jn + sc);
            v1 = *(const short8*)(Vbh + (sr + 32) * 2048 + jn + sc);
        }
        computeTile(it & 1);
        if (more) {
            const int nb = (it + 1) & 1;
            *(short8*)(&klds[nb][sr][sc]) = k0;
            *(short8*)(&klds[nb][sr + 32][sc]) = k1;
            *(short8*)(&vlds[nb][sr][sc]) = v0;
            *(short8*)(&vlds[nb][sr + 32][sc]) = v1;
        }
        __syncthreads();
    }

    lp += __shfl_xor(lp, 16);
    lp += __shfl_xor(lp, 32);
    const float invL = 1.0f / lp;

    const int n = q0 + w * 16 + ln;
    const int b = bh >> 3, h = bh & 7;
    short* abase = Aw + ((size_t)(b * 2048 + n) * 512) + h * 64 + quad * 4;
#pragma unroll
    for (int dt = 0; dt < 4; ++dt)
        *(bf16x4*)(abase + dt * 16) =
            pack4(ot[dt][0] * invL, ot[dt][1] * invL, ot[dt][2] * invL, ot[dt][3] * invL);
}

// ---------- 4) output GEMM + bias: coop staging, distance-2 prefetch ----------
// out_f32[4096][1024] = A_bf16[4096][512] @ Wo + bo; WoT[1024][512] bf16.
__global__ __launch_bounds__(256, 3) void gemm_final(const short* __restrict__ A,
                                                     const short* __restrict__ WoT,
                                                     const float* __restrict__ bias,
                                                     float* __restrict__ out) {
    const int tid = threadIdx.x;
    const int w = tid >> 6;
    const int lane = tid & 63;
    const int quad = lane >> 4, ln = lane & 15;
    const int wr = w >> 1, wc = w & 1;
    const int row0 = blockIdx.x * 64;
    const int col0 = blockIdx.y * 128;

    __shared__ __align__(16) short Alds[2][64][TPAD];
    __shared__ __align__(16) short Blds[2][128][TPAD];

    const int srow = tid >> 2;
    const int scol = (tid & 3) * 8;
    const short* aG = A + (size_t)(row0 + srow) * 512 + scol;
    const short* bG0 = WoT + (size_t)(col0 + srow) * 512 + scol;
    const short* bG1 = WoT + (size_t)(col0 + srow + 64) * 512 + scol;

    floatx4 acc[2][4] = {};
    short8 aR[2];
    short8 bR[2][2];

    auto loadStep = [&](int it, int set) {
        const int kk = it * 32;
        aR[set]    = *(const short8*)(aG + kk);
        bR[set][0] = *(const short8*)(bG0 + kk);
        bR[set][1] = *(const short8*)(bG1 + kk);
    };
    auto writeStep = [&](int buf, int set) {
        *(short8*)(&Alds[buf][srow][scol]) = aR[set];
        *(short8*)(&Blds[buf][srow][scol]) = bR[set][0];
        *(short8*)(&Blds[buf][srow + 64][scol]) = bR[set][1];
    };

    loadStep(0, 0);
    writeStep(0, 0);
    loadStep(1, 1);
    __syncthreads();

    const int nsteps = 512 / 32;
    for (int it = 0; it < nsteps; ++it) {
        const int buf = it & 1;
        if (it + 2 < nsteps) loadStep(it + 2, it & 1);
        if (it + 1 < nsteps) writeStep(buf ^ 1, (it + 1) & 1);
        short8 af[2], bf4[4];
#pragma unroll
        for (int i = 0; i < 2; ++i)
            af[i] = *(const short8*)(&Alds[buf][wr * 32 + i * 16 + ln][quad * 8]);
#pragma unroll
        for (int t = 0; t < 4; ++t)
            bf4[t] = *(const short8*)(&Blds[buf][wc * 64 + t * 16 + ln][quad * 8]);
#pragma unroll
        for (int i = 0; i < 2; ++i)
#pragma unroll
            for (int t = 0; t < 4; ++t)
                acc[i][t] = MFMA_BF16(af[i], bf4[t], acc[i][t]);
        __syncthreads();
    }

#pragma unroll
    for (int i = 0; i < 2; ++i)
#pragma unroll
        for (int t = 0; t < 4; ++t)
#pragma unroll
            for (int r = 0; r < 4; ++r) {
                const int R = row0 + wr * 32 + i * 16 + quad * 4 + r;
                const int C = col0 + wc * 64 + t * 16 + ln;
                out[(size_t)R * 1024 + C] = acc[i][t][r] + bias[C];
            }
}

// ---------- launcher ----------
extern "C" void kernel_launch(void* const* d_in, const int* in_sizes, int n_in,
                              void* d_out, int out_size, void* d_ws, size_t ws_size,
                              hipStream_t stream) {
    const float* x   = (const float*)d_in[0];  // [2,2048,1024] f32
    const float* ctx = (const float*)d_in[1];
    const float* Wq  = (const float*)d_in[2];  // [1024,512]
    const float* Wk  = (const float*)d_in[3];
    const float* Wv  = (const float*)d_in[4];
    const float* Wo  = (const float*)d_in[5];  // [512,1024]
    const float* bo  = (const float*)d_in[6];  // [1024]
    float* out = (float*)d_out;                // [2,2048,1024] f32

    char* ws = (char*)d_ws;
    size_t off = 0;
    auto alloc = [&](size_t bytes) { char* p = ws + off; off += (bytes + 255) & ~(size_t)255; return p; };

    short* WqT  = (short*)alloc(512 * 1024 * 2);     // [512][1024] bf16
    short* WkT  = (short*)alloc(512 * 1024 * 2);
    short* WvT  = (short*)alloc(512 * 1024 * 2);
    short* WoT  = (short*)alloc(1024 * 512 * 2);     // [1024][512] bf16
    short* Qw   = (short*)alloc((size_t)16 * 2048 * 64 * 2);
    short* Kw   = (short*)alloc((size_t)16 * 2048 * 64 * 2);
    short* Vtw  = (short*)alloc((size_t)16 * 2048 * 64 * 2);
    short* Aw   = (short*)alloc((size_t)4096 * 512 * 2);

    transpose_all<<<dim3(32, 32, 4), dim3(32, 8), 0, stream>>>(Wq, Wk, Wv, Wo, WqT, WkT, WvT, WoT);

    gemm_qkv<<<dim3(64, 4, 3), 256, 0, stream>>>(x, ctx, WqT, WkT, WvT, Qw, Kw, Vtw);

    attn_kernel<<<dim3(32, 16), 256, 0, stream>>>(Qw, Kw, Vtw, Aw);

    gemm_final<<<dim3(64, 8), 256, 0, stream>>>(Aw, WoT, bo, out);
}

// Round 11
// 167.873 us; speedup vs baseline: 1.2773x; 1.0063x over previous
//
#include <hip/hip_runtime.h>

// ---------- types / helpers ----------
typedef __attribute__((ext_vector_type(8))) short short8;   // 8 bf16 = 4 VGPRs
typedef __attribute__((ext_vector_type(4))) short bf16x4;   // 4 bf16 = 2 VGPRs
typedef __attribute__((ext_vector_type(4))) float floatx4;  // MFMA C/D
typedef __attribute__((ext_vector_type(4))) float f32x4;

__device__ __forceinline__ short f2bf(float f) {
    union { float f; unsigned u; } v;
    v.f = f;
    unsigned r = v.u + 0x7fffu + ((v.u >> 16) & 1u);  // RNE
    return (short)(r >> 16);
}
__device__ __forceinline__ short8 cvt8(f32x4 a, f32x4 b) {
    short8 r;
    r[0] = f2bf(a[0]); r[1] = f2bf(a[1]); r[2] = f2bf(a[2]); r[3] = f2bf(a[3]);
    r[4] = f2bf(b[0]); r[5] = f2bf(b[1]); r[6] = f2bf(b[2]); r[7] = f2bf(b[3]);
    return r;
}
// round-half-up f32->bf16 pack of 4
__device__ __forceinline__ bf16x4 pack4(float a, float b, float c, float d) {
    union { float f; unsigned u; } x;
    unsigned ua, ub, uc, ud;
    x.f = a; ua = (x.u + 0x8000u) >> 16;
    x.f = b; ub = (x.u + 0x8000u) >> 16;
    x.f = c; uc = (x.u + 0x8000u) >> 16;
    x.f = d; ud = (x.u + 0x8000u) >> 16;
    union { bf16x4 s; unsigned u2[2]; } r;
    r.u2[0] = ua | (ub << 16);
    r.u2[1] = uc | (ud << 16);
    return r.s;
}

#define MFMA_BF16(a, b, c) __builtin_amdgcn_mfma_f32_16x16x32_bf16((a), (b), (c), 0, 0, 0)

__device__ __forceinline__ floatx4 mfma16(bf16x4 a, bf16x4 b, floatx4 c) {
#if __has_builtin(__builtin_amdgcn_mfma_f32_16x16x16bf16_1k)
    return __builtin_amdgcn_mfma_f32_16x16x16bf16_1k(a, b, c, 0, 0, 0);
#else
    floatx4 d;
    asm volatile("v_mfma_f32_16x16x16_bf16 %0, %1, %2, %3"
                 : "=&v"(d) : "v"(a), "v"(b), "v"(c));
    return d;
#endif
}

__device__ __forceinline__ float fast_exp2(float x) {
#if __has_builtin(__builtin_amdgcn_exp2f)
    return __builtin_amdgcn_exp2f(x);
#else
    return exp2f(x);
#endif
}

// scale(1/8) * log2(e): softmax in exp2 domain, folded into Q at proj time
#define QSCALE_LOG2E 0.18033688011112042f

// ---------- 1) weights -> fragment-native layout WF[(k/8)][n][8], bf16 ----------
// One short8 at ((k>>3)*N + n)*8 is exactly the MFMA B-operand fragment
// (8 consecutive k) for column n. 65536 short8 outputs per weight for all z.
__global__ __launch_bounds__(256) void wfrag_all(const float* __restrict__ Wq,
                                                 const float* __restrict__ Wk,
                                                 const float* __restrict__ Wv,
                                                 const float* __restrict__ Wo,
                                                 short* __restrict__ WqF,
                                                 short* __restrict__ WkF,
                                                 short* __restrict__ WvF,
                                                 short* __restrict__ WoF) {
    const int z = blockIdx.y;
    const float* src = (z == 0) ? Wq : (z == 1) ? Wk : (z == 2) ? Wv : Wo;
    short* dst = (z == 0) ? WqF : (z == 1) ? WkF : (z == 2) ? WvF : WoF;
    const int nbits = (z < 3) ? 9 : 10;          // N = 512 or 1024
    const int N = 1 << nbits;
    const int t = blockIdx.x * 256 + threadIdx.x;  // 0..65535
    const int kb = t >> nbits;
    const int n = t & (N - 1);
    const float* s = src + (size_t)(kb * 8) * N + n;
    short8 v;
#pragma unroll
    for (int j = 0; j < 8; ++j) v[j] = f2bf(s[(size_t)j * N]);  // coalesced across lanes per j
    *(short8*)(dst + (size_t)t * 8) = v;
}

// ---------- 2) fused QKV projection GEMM: native-layout operands ----------
// C[4096][512] = A_f32[4096][1024] @ W ; WF[(k/8)][512][8] bf16 fragment-native.
// Block 256 thr (4 waves), BM=64 x BN=128, BK=32. A staged in LDS in native
// layout (8 KB dbl-buf, per-quad-contiguous frag reads); B direct-from-L2,
// fully coalesced (256 B/quad), register-prefetched distance-1.
__global__ __launch_bounds__(256, 3) void gemm_qkv(const float* __restrict__ x,
                                                   const float* __restrict__ ctx,
                                                   const short* __restrict__ WqF,
                                                   const short* __restrict__ WkF,
                                                   const short* __restrict__ WvF,
                                                   short* __restrict__ Qw,
                                                   short* __restrict__ Kw,
                                                   short* __restrict__ Vtw) {
    const int z = blockIdx.z;
    const float* A  = (z == 0) ? x : ctx;
    const short* WF = (z == 0) ? WqF : (z == 1) ? WkF : WvF;
    const int tid = threadIdx.x;
    const int w = tid >> 6;
    const int lane = tid & 63;
    const int quad = lane >> 4, ln = lane & 15;
    const int wr = w >> 1, wc = w & 1;
    const int row0 = blockIdx.x * 64;
    const int col0 = blockIdx.y * 128;

    __shared__ __align__(16) short Alds[2][2048];  // native: (kseg*64 + row)*8

    const int srow = tid >> 2;          // 0..63
    const int sseg = tid & 3;           // k-block of 8 within the 32-k step
    const float* aG = A + (size_t)(row0 + srow) * 1024 + sseg * 8;

    const short* bG[4];
#pragma unroll
    for (int t = 0; t < 4; ++t)
        bG[t] = WF + ((size_t)quad * 512 + col0 + wc * 64 + t * 16 + ln) * 8;

    floatx4 acc[2][4] = {};
    f32x4 aR[2][2];
    short8 bR[2][4];

    auto loadA = [&](int it, int set) {
        aR[set][0] = *(const f32x4*)(aG + it * 32);
        aR[set][1] = *(const f32x4*)(aG + it * 32 + 4);
    };
    auto writeA = [&](int buf, int set) {
        *(short8*)(&Alds[buf][(sseg * 64 + srow) * 8]) = cvt8(aR[set][0], aR[set][1]);
    };
    auto loadB = [&](int it, int set) {
#pragma unroll
        for (int t = 0; t < 4; ++t)
            bR[set][t] = *(const short8*)(bG[t] + (size_t)it * 16384);  // 4*512*8 shorts/step
    };

    loadA(0, 0);
    writeA(0, 0);
    loadA(1, 1);
    loadB(0, 0);
    __syncthreads();

    const int nsteps = 1024 / 32;
    for (int it = 0; it < nsteps; ++it) {
        const int buf = it & 1;
        if (it + 2 < nsteps) loadA(it + 2, it & 1);
        if (it + 1 < nsteps) {
            loadB(it + 1, (it + 1) & 1);
            writeA(buf ^ 1, (it + 1) & 1);
        }
        short8 af[2];
#pragma unroll
        for (int i = 0; i < 2; ++i)
            af[i] = *(const short8*)(&Alds[buf][quad * 512 + (wr * 32 + i * 16 + ln) * 8]);
#pragma unroll
        for (int i = 0; i < 2; ++i)
#pragma unroll
            for (int t = 0; t < 4; ++t)
                acc[i][t] = MFMA_BF16(af[i], bR[it & 1][t], acc[i][t]);
        __syncthreads();
    }

    const float oscale = (z == 0) ? QSCALE_LOG2E : 1.0f;
    short* dst = (z == 0) ? Qw : (z == 1) ? Kw : Vtw;
#pragma unroll
    for (int i = 0; i < 2; ++i)
#pragma unroll
        for (int t = 0; t < 4; ++t)
#pragma unroll
            for (int r = 0; r < 4; ++r) {
                const int R = row0 + wr * 32 + i * 16 + quad * 4 + r;
                const int C = col0 + wc * 64 + t * 16 + ln;
                const int b = R >> 11, n = R & 2047;
                const int h = C >> 6, d = C & 63;
                const short val = f2bf(acc[i][t][r] * oscale);
                if (z < 2)
                    dst[((b * 8 + h) * 2048 + n) * 64 + d] = val;
                else
                    dst[((b * 8 + h) * 64 + d) * 2048 + n] = val;
            }
}

// ---------- 3) flash attention (round-8 structure: staged K/V, S^T trick) ----------
__global__ __launch_bounds__(256, 2) void attn_kernel(const short* __restrict__ Q,
                                                      const short* __restrict__ K,
                                                      const short* __restrict__ Vt,
                                                      short* __restrict__ Aw) {
    const int tid = threadIdx.x;
    const int w = tid >> 6;
    const int lane = tid & 63;
    const int quad = lane >> 4;
    const int ln = lane & 15;
    const int q0 = blockIdx.x * 64;
    const int bh = blockIdx.y;  // b*8+h

    __shared__ __align__(16) short klds[2][64][72];
    __shared__ __align__(16) short vlds[2][64][72];

    const short* Qbh = Q + bh * 2048 * 64;
    const short* Kbh = K + bh * 2048 * 64;
    const short* Vbh = Vt + bh * 64 * 2048;

    short8 qf[2];
    {
        const int qrow = q0 + w * 16 + ln;
        qf[0] = *(const short8*)(Qbh + qrow * 64 + quad * 8);
        qf[1] = *(const short8*)(Qbh + qrow * 64 + 32 + quad * 8);
    }

    floatx4 ot[4] = {};   // O^T: lane holds d=dt*16+quad*4+r, qrow=ln
    float lp = 0.f;

    const int sr = tid >> 3;
    const int sc = (tid & 7) * 8;

    auto computeTile = [&](int b) {
        short8 kf[8];
#pragma unroll
        for (int t = 0; t < 4; ++t)
#pragma unroll
            for (int ks = 0; ks < 2; ++ks)
                kf[t * 2 + ks] = *(const short8*)(&klds[b][t * 16 + ln][ks * 32 + quad * 8]);
        bf16x4 vf[16];
#pragma unroll
        for (int dt = 0; dt < 4; ++dt)
#pragma unroll
            for (int t = 0; t < 4; ++t)
                vf[dt * 4 + t] = *(const bf16x4*)(&vlds[b][dt * 16 + ln][t * 16 + quad * 4]);

        floatx4 s[4] = {};
#pragma unroll
        for (int ks = 0; ks < 2; ++ks)
#pragma unroll
            for (int t = 0; t < 4; ++t)
                s[t] = MFMA_BF16(kf[t * 2 + ks], qf[ks], s[t]);

        bf16x4 pf[4];
#pragma unroll
        for (int t = 0; t < 4; ++t) {
            float p0 = fast_exp2(s[t][0]);
            float p1 = fast_exp2(s[t][1]);
            float p2 = fast_exp2(s[t][2]);
            float p3 = fast_exp2(s[t][3]);
            lp += (p0 + p1) + (p2 + p3);
            pf[t] = pack4(p0, p1, p2, p3);
        }
#pragma unroll
        for (int t = 0; t < 4; ++t)
#pragma unroll
            for (int dt = 0; dt < 4; ++dt)
                ot[dt] = mfma16(vf[dt * 4 + t], pf[t], ot[dt]);
    };

    const int nt = 2048 / 64;

    {   // prologue: stage tile 0
        short8 k0 = *(const short8*)(Kbh + tid * 8);
        short8 k1 = *(const short8*)(Kbh + (tid + 256) * 8);
        short8 v0 = *(const short8*)(Vbh + sr * 2048 + sc);
        short8 v1 = *(const short8*)(Vbh + (sr + 32) * 2048 + sc);
        *(short8*)(&klds[0][sr][sc]) = k0;
        *(short8*)(&klds[0][sr + 32][sc]) = k1;
        *(short8*)(&vlds[0][sr][sc]) = v0;
        *(short8*)(&vlds[0][sr + 32][sc]) = v1;
    }
    __syncthreads();

    for (int it = 0; it < nt; ++it) {
        short8 k0, k1, v0, v1;
        const bool more = (it + 1 < nt);
        if (more) {
            const int jn = (it + 1) * 64;
            k0 = *(const short8*)(Kbh + jn * 64 + tid * 8);
            k1 = *(const short8*)(Kbh + jn * 64 + (tid + 256) * 8);
            v0 = *(const short8*)(Vbh + sr * 2048 + jn + sc);
            v1 = *(const short8*)(Vbh + (sr + 32) * 2048 + jn + sc);
        }
        computeTile(it & 1);
        if (more) {
            const int nb = (it + 1) & 1;
            *(short8*)(&klds[nb][sr][sc]) = k0;
            *(short8*)(&klds[nb][sr + 32][sc]) = k1;
            *(short8*)(&vlds[nb][sr][sc]) = v0;
            *(short8*)(&vlds[nb][sr + 32][sc]) = v1;
        }
        __syncthreads();
    }

    lp += __shfl_xor(lp, 16);
    lp += __shfl_xor(lp, 32);
    const float invL = 1.0f / lp;

    const int n = q0 + w * 16 + ln;
    const int b = bh >> 3, h = bh & 7;
    short* abase = Aw + ((size_t)(b * 2048 + n) * 512) + h * 64 + quad * 4;
#pragma unroll
    for (int dt = 0; dt < 4; ++dt)
        *(bf16x4*)(abase + dt * 16) =
            pack4(ot[dt][0] * invL, ot[dt][1] * invL, ot[dt][2] * invL, ot[dt][3] * invL);
}

// ---------- 4) output GEMM + bias: native-layout operands ----------
// out_f32[4096][1024] = A_bf16[4096][512] @ Wo + bo; WoF[(k/8)][1024][8] bf16.
__global__ __launch_bounds__(256, 2) void gemm_final(const short* __restrict__ A,
                                                     const short* __restrict__ WoF,
                                                     const float* __restrict__ bias,
                                                     float* __restrict__ out) {
    const int tid = threadIdx.x;
    const int w = tid >> 6;
    const int lane = tid & 63;
    const int quad = lane >> 4, ln = lane & 15;
    const int wr = w >> 1, wc = w & 1;
    const int row0 = blockIdx.x * 64;
    const int col0 = blockIdx.y * 128;

    __shared__ __align__(16) short Alds[2][2048];

    const int srow = tid >> 2;
    const int sseg = tid & 3;
    const short* aG = A + (size_t)(row0 + srow) * 512 + sseg * 8;

    const short* bG[4];
#pragma unroll
    for (int t = 0; t < 4; ++t)
        bG[t] = WoF + ((size_t)quad * 1024 + col0 + wc * 64 + t * 16 + ln) * 8;

    floatx4 acc[2][4] = {};
    short8 aR[2];
    short8 bR[2][4];

    auto loadA = [&](int it, int set) { aR[set] = *(const short8*)(aG + it * 32); };
    auto writeA = [&](int buf, int set) {
        *(short8*)(&Alds[buf][(sseg * 64 + srow) * 8]) = aR[set];
    };
    auto loadB = [&](int it, int set) {
#pragma unroll
        for (int t = 0; t < 4; ++t)
            bR[set][t] = *(const short8*)(bG[t] + (size_t)it * 32768);  // 4*1024*8 shorts/step
    };

    loadA(0, 0);
    writeA(0, 0);
    loadA(1, 1);
    loadB(0, 0);
    __syncthreads();

    const int nsteps = 512 / 32;
    for (int it = 0; it < nsteps; ++it) {
        const int buf = it & 1;
        if (it + 2 < nsteps) loadA(it + 2, it & 1);
        if (it + 1 < nsteps) {
            loadB(it + 1, (it + 1) & 1);
            writeA(buf ^ 1, (it + 1) & 1);
        }
        short8 af[2];
#pragma unroll
        for (int i = 0; i < 2; ++i)
            af[i] = *(const short8*)(&Alds[buf][quad * 512 + (wr * 32 + i * 16 + ln) * 8]);
#pragma unroll
        for (int i = 0; i < 2; ++i)
#pragma unroll
            for (int t = 0; t < 4; ++t)
                acc[i][t] = MFMA_BF16(af[i], bR[it & 1][t], acc[i][t]);
        __syncthreads();
    }

#pragma unroll
    for (int i = 0; i < 2; ++i)
#pragma unroll
        for (int t = 0; t < 4; ++t)
#pragma unroll
            for (int r = 0; r < 4; ++r) {
                const int R = row0 + wr * 32 + i * 16 + quad * 4 + r;
                const int C = col0 + wc * 64 + t * 16 + ln;
                out[(size_t)R * 1024 + C] = acc[i][t][r] + bias[C];
            }
}

// ---------- launcher ----------
extern "C" void kernel_launch(void* const* d_in, const int* in_sizes, int n_in,
                              void* d_out, int out_size, void* d_ws, size_t ws_size,
                              hipStream_t stream) {
    const float* x   = (const float*)d_in[0];  // [2,2048,1024] f32
    const float* ctx = (const float*)d_in[1];
    const float* Wq  = (const float*)d_in[2];  // [1024,512]
    const float* Wk  = (const float*)d_in[3];
    const float* Wv  = (const float*)d_in[4];
    const float* Wo  = (const float*)d_in[5];  // [512,1024]
    const float* bo  = (const float*)d_in[6];  // [1024]
    float* out = (float*)d_out;                // [2,2048,1024] f32

    char* ws = (char*)d_ws;
    size_t off = 0;
    auto alloc = [&](size_t bytes) { char* p = ws + off; off += (bytes + 255) & ~(size_t)255; return p; };

    short* WqF  = (short*)alloc(512 * 1024 * 2);     // fragment-native bf16
    short* WkF  = (short*)alloc(512 * 1024 * 2);
    short* WvF  = (short*)alloc(512 * 1024 * 2);
    short* WoF  = (short*)alloc(1024 * 512 * 2);
    short* Qw   = (short*)alloc((size_t)16 * 2048 * 64 * 2);
    short* Kw   = (short*)alloc((size_t)16 * 2048 * 64 * 2);
    short* Vtw  = (short*)alloc((size_t)16 * 2048 * 64 * 2);
    short* Aw   = (short*)alloc((size_t)4096 * 512 * 2);

    wfrag_all<<<dim3(256, 4), 256, 0, stream>>>(Wq, Wk, Wv, Wo, WqF, WkF, WvF, WoF);

    gemm_qkv<<<dim3(64, 4, 3), 256, 0, stream>>>(x, ctx, WqF, WkF, WvF, Qw, Kw, Vtw);

    attn_kernel<<<dim3(32, 16), 256, 0, stream>>>(Qw, Kw, Vtw, Aw);

    gemm_final<<<dim3(64, 8), 256, 0, stream>>>(Aw, WoF, bo, out);
}

// Round 12
// 166.377 us; speedup vs baseline: 1.2888x; 1.0090x over previous
//
#include <hip/hip_runtime.h>

// ---------- types / helpers ----------
typedef __attribute__((ext_vector_type(8))) short short8;   // 8 bf16 = 4 VGPRs
typedef __attribute__((ext_vector_type(4))) short bf16x4;   // 4 bf16 = 2 VGPRs
typedef __attribute__((ext_vector_type(4))) float floatx4;  // MFMA C/D
typedef __attribute__((ext_vector_type(4))) float f32x4;

__device__ __forceinline__ short f2bf(float f) {
    union { float f; unsigned u; } v;
    v.f = f;
    unsigned r = v.u + 0x7fffu + ((v.u >> 16) & 1u);  // RNE
    return (short)(r >> 16);
}
__device__ __forceinline__ short8 cvt8(f32x4 a, f32x4 b) {
    short8 r;
    r[0] = f2bf(a[0]); r[1] = f2bf(a[1]); r[2] = f2bf(a[2]); r[3] = f2bf(a[3]);
    r[4] = f2bf(b[0]); r[5] = f2bf(b[1]); r[6] = f2bf(b[2]); r[7] = f2bf(b[3]);
    return r;
}
// round-half-up f32->bf16 pack of 4
__device__ __forceinline__ bf16x4 pack4(float a, float b, float c, float d) {
    union { float f; unsigned u; } x;
    unsigned ua, ub, uc, ud;
    x.f = a; ua = (x.u + 0x8000u) >> 16;
    x.f = b; ub = (x.u + 0x8000u) >> 16;
    x.f = c; uc = (x.u + 0x8000u) >> 16;
    x.f = d; ud = (x.u + 0x8000u) >> 16;
    union { bf16x4 s; unsigned u2[2]; } r;
    r.u2[0] = ua | (ub << 16);
    r.u2[1] = uc | (ud << 16);
    return r.s;
}

#define MFMA_BF16(a, b, c) __builtin_amdgcn_mfma_f32_16x16x32_bf16((a), (b), (c), 0, 0, 0)

__device__ __forceinline__ floatx4 mfma16(bf16x4 a, bf16x4 b, floatx4 c) {
#if __has_builtin(__builtin_amdgcn_mfma_f32_16x16x16bf16_1k)
    return __builtin_amdgcn_mfma_f32_16x16x16bf16_1k(a, b, c, 0, 0, 0);
#else
    floatx4 d;
    asm volatile("v_mfma_f32_16x16x16_bf16 %0, %1, %2, %3"
                 : "=&v"(d) : "v"(a), "v"(b), "v"(c));
    return d;
#endif
}

__device__ __forceinline__ float fast_exp2(float x) {
#if __has_builtin(__builtin_amdgcn_exp2f)
    return __builtin_amdgcn_exp2f(x);
#else
    return exp2f(x);
#endif
}

// scale(1/8) * log2(e): softmax in exp2 domain, folded into Q at proj time
#define QSCALE_LOG2E 0.18033688011112042f

// ---------- 1) weights -> fragment-native WF[(k/8)][n][8], bf16 ----------
__global__ __launch_bounds__(256) void wfrag_all(const float* __restrict__ Wq,
                                                 const float* __restrict__ Wk,
                                                 const float* __restrict__ Wv,
                                                 const float* __restrict__ Wo,
                                                 short* __restrict__ WqF,
                                                 short* __restrict__ WkF,
                                                 short* __restrict__ WvF,
                                                 short* __restrict__ WoF) {
    const int z = blockIdx.y;
    const float* src = (z == 0) ? Wq : (z == 1) ? Wk : (z == 2) ? Wv : Wo;
    short* dst = (z == 0) ? WqF : (z == 1) ? WkF : (z == 2) ? WvF : WoF;
    const int nbits = (z < 3) ? 9 : 10;          // N = 512 or 1024
    const int N = 1 << nbits;
    const int t = blockIdx.x * 256 + threadIdx.x;  // 0..65535
    const int kb = t >> nbits;
    const int n = t & (N - 1);
    const float* s = src + (size_t)(kb * 8) * N + n;
    short8 v;
#pragma unroll
    for (int j = 0; j < 8; ++j) v[j] = f2bf(s[(size_t)j * N]);
    *(short8*)(dst + (size_t)t * 8) = v;
}

// ---------- 2) activations -> fragment-native AF[(k/8)][row][8], bf16 ----------
// 64-row x 64-k tiles via LDS; coalesced reads (along k) and writes (along row).
__global__ __launch_bounds__(256) void afrag(const float* __restrict__ x,
                                             const float* __restrict__ ctx,
                                             short* __restrict__ AxF,
                                             short* __restrict__ AcF) {
    const float* src = (blockIdx.z == 0) ? x : ctx;
    short* dst = (blockIdx.z == 0) ? AxF : AcF;
    const int r0 = blockIdx.x * 64;
    const int k0 = blockIdx.y * 64;
    __shared__ short tile[64][72];
    const int tid = threadIdx.x;
    {
        const int seg = tid & 15;        // 16 x f32x4 per row
        const int rbase = tid >> 4;      // 0..15
#pragma unroll
        for (int i = 0; i < 4; ++i) {
            const int row = rbase + i * 16;
            f32x4 v = *(const f32x4*)(src + (size_t)(r0 + row) * 1024 + k0 + seg * 4);
#pragma unroll
            for (int jj = 0; jj < 4; ++jj) tile[row][seg * 4 + jj] = f2bf(v[jj]);
        }
    }
    __syncthreads();
    {
        const int kbl = tid >> 5;        // 0..7
        const int rbase = tid & 31;
#pragma unroll
        for (int j = 0; j < 2; ++j) {
            const int row = rbase + j * 32;
            short8 v = *(const short8*)(&tile[row][kbl * 8]);
            *(short8*)(dst + ((size_t)(k0 / 8 + kbl) * 4096 + r0 + row) * 8) = v;
        }
    }
}

// ---------- 3) fused QKV projection GEMM: no LDS, no barriers ----------
// Both operands fragment-native; rotating 3-set register pipeline (distance 2).
// Block 256 thr (4 waves), BM=64 x BN=128, wave tile 32x64, 32 K-steps.
__global__ __launch_bounds__(256, 4) void gemm_qkv(const short* __restrict__ AxF,
                                                   const short* __restrict__ AcF,
                                                   const short* __restrict__ WqF,
                                                   const short* __restrict__ WkF,
                                                   const short* __restrict__ WvF,
                                                   short* __restrict__ Qw,
                                                   short* __restrict__ Kw,
                                                   short* __restrict__ Vtw) {
    const int z = blockIdx.z;
    const short* AF = (z == 0) ? AxF : AcF;
    const short* WF = (z == 0) ? WqF : (z == 1) ? WkF : WvF;
    const int tid = threadIdx.x;
    const int w = tid >> 6;
    const int lane = tid & 63;
    const int quad = lane >> 4, ln = lane & 15;
    const int wr = w >> 1, wc = w & 1;
    const int row0 = blockIdx.x * 64;
    const int col0 = blockIdx.y * 128;

    const short* aBase = AF + ((size_t)quad * 4096 + row0 + wr * 32 + ln) * 8;
    const short* bBase = WF + ((size_t)quad * 512 + col0 + wc * 64 + ln) * 8;

    floatx4 acc[2][4] = {};
    short8 aR[3][2], bR[3][4];

    auto loadStep = [&](int it) {
        const int s = it % 3;
#pragma unroll
        for (int i = 0; i < 2; ++i)
            aR[s][i] = *(const short8*)(aBase + (size_t)it * 131072 + i * 128);
#pragma unroll
        for (int t = 0; t < 4; ++t)
            bR[s][t] = *(const short8*)(bBase + (size_t)it * 16384 + t * 128);
    };

    loadStep(0);
    loadStep(1);
#pragma unroll
    for (int it = 0; it < 32; ++it) {
        if (it + 2 < 32) loadStep(it + 2);
        const int s = it % 3;
#pragma unroll
        for (int i = 0; i < 2; ++i)
#pragma unroll
            for (int t = 0; t < 4; ++t)
                acc[i][t] = MFMA_BF16(aR[s][i], bR[s][t], acc[i][t]);
    }

    const float oscale = (z == 0) ? QSCALE_LOG2E : 1.0f;
    short* dst = (z == 0) ? Qw : (z == 1) ? Kw : Vtw;
#pragma unroll
    for (int i = 0; i < 2; ++i)
#pragma unroll
        for (int t = 0; t < 4; ++t)
#pragma unroll
            for (int r = 0; r < 4; ++r) {
                const int R = row0 + wr * 32 + i * 16 + quad * 4 + r;
                const int C = col0 + wc * 64 + t * 16 + ln;
                const int b = R >> 11, n = R & 2047;
                const int h = C >> 6, d = C & 63;
                const short val = f2bf(acc[i][t][r] * oscale);
                if (z < 2)
                    dst[((b * 8 + h) * 2048 + n) * 64 + d] = val;
                else
                    dst[((b * 8 + h) * 64 + d) * 2048 + n] = val;
            }
}

// ---------- 4) flash attention (round-8 structure); epilogue writes AwF native ----------
__global__ __launch_bounds__(256, 2) void attn_kernel(const short* __restrict__ Q,
                                                      const short* __restrict__ K,
                                                      const short* __restrict__ Vt,
                                                      short* __restrict__ AwF) {
    const int tid = threadIdx.x;
    const int w = tid >> 6;
    const int lane = tid & 63;
    const int quad = lane >> 4;
    const int ln = lane & 15;
    const int q0 = blockIdx.x * 64;
    const int bh = blockIdx.y;  // b*8+h

    __shared__ __align__(16) short klds[2][64][72];
    __shared__ __align__(16) short vlds[2][64][72];

    const short* Qbh = Q + bh * 2048 * 64;
    const short* Kbh = K + bh * 2048 * 64;
    const short* Vbh = Vt + bh * 64 * 2048;

    short8 qf[2];
    {
        const int qrow = q0 + w * 16 + ln;
        qf[0] = *(const short8*)(Qbh + qrow * 64 + quad * 8);
        qf[1] = *(const short8*)(Qbh + qrow * 64 + 32 + quad * 8);
    }

    floatx4 ot[4] = {};   // O^T: lane holds d=dt*16+quad*4+r, qrow=ln
    float lp = 0.f;

    const int sr = tid >> 3;
    const int sc = (tid & 7) * 8;

    auto computeTile = [&](int b) {
        short8 kf[8];
#pragma unroll
        for (int t = 0; t < 4; ++t)
#pragma unroll
            for (int ks = 0; ks < 2; ++ks)
                kf[t * 2 + ks] = *(const short8*)(&klds[b][t * 16 + ln][ks * 32 + quad * 8]);
        bf16x4 vf[16];
#pragma unroll
        for (int dt = 0; dt < 4; ++dt)
#pragma unroll
            for (int t = 0; t < 4; ++t)
                vf[dt * 4 + t] = *(const bf16x4*)(&vlds[b][dt * 16 + ln][t * 16 + quad * 4]);

        floatx4 s[4] = {};
#pragma unroll
        for (int ks = 0; ks < 2; ++ks)
#pragma unroll
            for (int t = 0; t < 4; ++t)
                s[t] = MFMA_BF16(kf[t * 2 + ks], qf[ks], s[t]);

        bf16x4 pf[4];
#pragma unroll
        for (int t = 0; t < 4; ++t) {
            float p0 = fast_exp2(s[t][0]);
            float p1 = fast_exp2(s[t][1]);
            float p2 = fast_exp2(s[t][2]);
            float p3 = fast_exp2(s[t][3]);
            lp += (p0 + p1) + (p2 + p3);
            pf[t] = pack4(p0, p1, p2, p3);
        }
#pragma unroll
        for (int t = 0; t < 4; ++t)
#pragma unroll
            for (int dt = 0; dt < 4; ++dt)
                ot[dt] = mfma16(vf[dt * 4 + t], pf[t], ot[dt]);
    };

    const int nt = 2048 / 64;

    {   // prologue: stage tile 0
        short8 k0 = *(const short8*)(Kbh + tid * 8);
        short8 k1 = *(const short8*)(Kbh + (tid + 256) * 8);
        short8 v0 = *(const short8*)(Vbh + sr * 2048 + sc);
        short8 v1 = *(const short8*)(Vbh + (sr + 32) * 2048 + sc);
        *(short8*)(&klds[0][sr][sc]) = k0;
        *(short8*)(&klds[0][sr + 32][sc]) = k1;
        *(short8*)(&vlds[0][sr][sc]) = v0;
        *(short8*)(&vlds[0][sr + 32][sc]) = v1;
    }
    __syncthreads();

    for (int it = 0; it < nt; ++it) {
        short8 k0, k1, v0, v1;
        const bool more = (it + 1 < nt);
        if (more) {
            const int jn = (it + 1) * 64;
            k0 = *(const short8*)(Kbh + jn * 64 + tid * 8);
            k1 = *(const short8*)(Kbh + jn * 64 + (tid + 256) * 8);
            v0 = *(const short8*)(Vbh + sr * 2048 + jn + sc);
            v1 = *(const short8*)(Vbh + (sr + 32) * 2048 + jn + sc);
        }
        computeTile(it & 1);
        if (more) {
            const int nb = (it + 1) & 1;
            *(short8*)(&klds[nb][sr][sc]) = k0;
            *(short8*)(&klds[nb][sr + 32][sc]) = k1;
            *(short8*)(&vlds[nb][sr][sc]) = v0;
            *(short8*)(&vlds[nb][sr + 32][sc]) = v1;
        }
        __syncthreads();
    }

    lp += __shfl_xor(lp, 16);
    lp += __shfl_xor(lp, 32);
    const float invL = 1.0f / lp;

    // epilogue: write fragment-native AwF[(k/8)][R][8], k = h*64+d, R = b*2048+n
    const int n = q0 + w * 16 + ln;
    const int b = bh >> 3, h = bh & 7;
    const int R = b * 2048 + n;
#pragma unroll
    for (int dt = 0; dt < 4; ++dt) {
        const int kb = h * 8 + dt * 2 + (quad >> 1);
        short* p = AwF + ((size_t)kb * 4096 + R) * 8 + (quad & 1) * 4;
        *(bf16x4*)p = pack4(ot[dt][0] * invL, ot[dt][1] * invL,
                            ot[dt][2] * invL, ot[dt][3] * invL);
    }
}

// ---------- 5) output GEMM + bias: no LDS, no barriers ----------
// out_f32[4096][1024] = AwF (native) @ WoF (native) + bo; 16 K-steps.
__global__ __launch_bounds__(256, 4) void gemm_final(const short* __restrict__ AwF,
                                                     const short* __restrict__ WoF,
                                                     const float* __restrict__ bias,
                                                     float* __restrict__ out) {
    const int tid = threadIdx.x;
    const int w = tid >> 6;
    const int lane = tid & 63;
    const int quad = lane >> 4, ln = lane & 15;
    const int wr = w >> 1, wc = w & 1;
    const int row0 = blockIdx.x * 64;
    const int col0 = blockIdx.y * 128;

    const short* aBase = AwF + ((size_t)quad * 4096 + row0 + wr * 32 + ln) * 8;
    const short* bBase = WoF + ((size_t)quad * 1024 + col0 + wc * 64 + ln) * 8;

    floatx4 acc[2][4] = {};
    short8 aR[3][2], bR[3][4];

    auto loadStep = [&](int it) {
        const int s = it % 3;
#pragma unroll
        for (int i = 0; i < 2; ++i)
            aR[s][i] = *(const short8*)(aBase + (size_t)it * 131072 + i * 128);
#pragma unroll
        for (int t = 0; t < 4; ++t)
            bR[s][t] = *(const short8*)(bBase + (size_t)it * 32768 + t * 128);
    };

    loadStep(0);
    loadStep(1);
#pragma unroll
    for (int it = 0; it < 16; ++it) {
        if (it + 2 < 16) loadStep(it + 2);
        const int s = it % 3;
#pragma unroll
        for (int i = 0; i < 2; ++i)
#pragma unroll
            for (int t = 0; t < 4; ++t)
                acc[i][t] = MFMA_BF16(aR[s][i], bR[s][t], acc[i][t]);
    }

#pragma unroll
    for (int i = 0; i < 2; ++i)
#pragma unroll
        for (int t = 0; t < 4; ++t)
#pragma unroll
            for (int r = 0; r < 4; ++r) {
                const int R = row0 + wr * 32 + i * 16 + quad * 4 + r;
                const int C = col0 + wc * 64 + t * 16 + ln;
                out[(size_t)R * 1024 + C] = acc[i][t][r] + bias[C];
            }
}

// ---------- launcher ----------
extern "C" void kernel_launch(void* const* d_in, const int* in_sizes, int n_in,
                              void* d_out, int out_size, void* d_ws, size_t ws_size,
                              hipStream_t stream) {
    const float* x   = (const float*)d_in[0];  // [2,2048,1024] f32
    const float* ctx = (const float*)d_in[1];
    const float* Wq  = (const float*)d_in[2];  // [1024,512]
    const float* Wk  = (const float*)d_in[3];
    const float* Wv  = (const float*)d_in[4];
    const float* Wo  = (const float*)d_in[5];  // [512,1024]
    const float* bo  = (const float*)d_in[6];  // [1024]
    float* out = (float*)d_out;                // [2,2048,1024] f32

    char* ws = (char*)d_ws;
    size_t off = 0;
    auto alloc = [&](size_t bytes) { char* p = ws + off; off += (bytes + 255) & ~(size_t)255; return p; };

    short* WqF  = (short*)alloc(512 * 1024 * 2);        // fragment-native bf16
    short* WkF  = (short*)alloc(512 * 1024 * 2);
    short* WvF  = (short*)alloc(512 * 1024 * 2);
    short* WoF  = (short*)alloc(1024 * 512 * 2);
    short* AxF  = (short*)alloc((size_t)4096 * 1024 * 2);  // x native
    short* AcF  = (short*)alloc((size_t)4096 * 1024 * 2);  // ctx native
    short* Qw   = (short*)alloc((size_t)16 * 2048 * 64 * 2);
    short* Kw   = (short*)alloc((size_t)16 * 2048 * 64 * 2);
    short* Vtw  = (short*)alloc((size_t)16 * 2048 * 64 * 2);
    short* AwF  = (short*)alloc((size_t)4096 * 512 * 2);   // attn out, native

    wfrag_all<<<dim3(256, 4), 256, 0, stream>>>(Wq, Wk, Wv, Wo, WqF, WkF, WvF, WoF);
    afrag<<<dim3(64, 16, 2), 256, 0, stream>>>(x, ctx, AxF, AcF);

    gemm_qkv<<<dim3(64, 4, 3), 256, 0, stream>>>(AxF, AcF, WqF, WkF, WvF, Qw, Kw, Vtw);

    attn_kernel<<<dim3(32, 16), 256, 0, stream>>>(Qw, Kw, Vtw, AwF);

    gemm_final<<<dim3(64, 8), 256, 0, stream>>>(AwF, WoF, bo, out);
}